// Round 4
// baseline (210.620 us; speedup 1.0000x reference)
//
#include <hip/hip_runtime.h>
#include <hip/hip_cooperative_groups.h>
namespace cg = cooperative_groups;

#define G 5000
#define K 256
#define BATCH 16
#define HID 64
#define STEPS 10
#define NCH 64          // gene chunks (one per block-group of 4)
#define GPER 79         // 64*79 = 5056 >= 5000
#define NCP 256         // partial slots = NCH * 4 subs
#define NBLK 256        // 1 block/CU, trivially co-resident
#define NTHR 1024

// ---------------------------------------------------------------------------
// Single cooperative kernel, 3 phases split by grid.sync():
//  P1: partial max-pool  (all 256 blocks; block=(chunk,bgroup), thr=(k,sub))
//  P2: APPNP chain       (blocks 0..15, one per batch row; A register-stationary)
//  P3: z_gene @ M^T + MLP (blocks 0..78, one 64-gene x 16-batch tile each)
// All FMA chains keep the round-3 order -> bitwise-identical output.
// ---------------------------------------------------------------------------
__global__ __launch_bounds__(NTHR, 4)
void fused_all(const float* __restrict__ ctl,
               const float* __restrict__ tgt,
               const int* __restrict__ cell_idx,
               const float* __restrict__ M,
               const float* __restrict__ A,
               const float* __restrict__ W1,
               const float* __restrict__ b1,
               const float* __restrict__ cell_emb,
               const float* __restrict__ W2,
               const float* __restrict__ b2,
               float* __restrict__ out,
               float* __restrict__ partials,   // NCP*16*256
               float* __restrict__ Zfin,       // 16*256
               float* __restrict__ ce_dot) {   // 16
    cg::grid_group grid = cg::this_grid();

    __shared__ float4 tl[GPER];          // P1: t values per gene, 4 batches
    __shared__ float  Sm[K];             // P2
    __shared__ float  red[4][K];         // P2
    __shared__ float  ce_red[HID];       // P2
    __shared__ float4 zb[2][K / 4];      // P2: double-buffered Z row
    __shared__ float4 zl[BATCH * (K/4)]; // P3: all Z rows (16 KB)
    __shared__ float4 wpack[HID];        // P3: (W1r0,W1r1,W1r2,b1)
    __shared__ float  w2l[HID];          // P3

    const int blk = blockIdx.x;
    const int tid = threadIdx.x;

    // ================= Phase 1: max-pool partials =================
    {
        const int c   = blk >> 2;         // chunk 0..63
        const int bg  = blk & 3;          // batch group 0..3
        const int b0  = bg * 4;
        const int g0  = c * GPER;
        const int cnt = min(GPER, G - g0);
        const int k   = tid & 255;
        const int sub = tid >> 8;         // 0..3, wave-uniform

        if (tid < cnt) {
            int g = g0 + tid;
            tl[tid] = make_float4(tgt[(b0+0)*G + g], tgt[(b0+1)*G + g],
                                  tgt[(b0+2)*G + g], tgt[(b0+3)*G + g]);
        }
        __syncthreads();

        const int s0 = sub * 20;
        const int s1 = min(cnt, s0 + 20);
        float mx0 = 0.f, mx1 = 0.f, mx2 = 0.f, mx3 = 0.f;
        for (int gi = s0; gi < s1; ++gi) {
            float mg = M[(size_t)(g0 + gi) * K + k];   // coalesced across k
            float4 tv = tl[gi];                        // LDS broadcast
            mx0 = fmaxf(mx0, tv.x * mg);
            mx1 = fmaxf(mx1, tv.y * mg);
            mx2 = fmaxf(mx2, tv.z * mg);
            mx3 = fmaxf(mx3, tv.w * mg);
        }
        const int cp = (c << 2) | sub;    // 0..255; every slot gets written
        partials[((size_t)cp * BATCH + b0+0) * K + k] = mx0;
        partials[((size_t)cp * BATCH + b0+1) * K + k] = mx1;
        partials[((size_t)cp * BATCH + b0+2) * K + k] = mx2;
        partials[((size_t)cp * BATCH + b0+3) * K + k] = mx3;
    }
    grid.sync();

    // ================= Phase 2: APPNP (blocks 0..15) =================
    if (blk < BATCH) {
        const int b  = blk;
        const int k  = tid & 255;
        const int jc = tid >> 8;          // 0..3, wave-uniform
        const int j0 = jc * 64;

        // A column-slice stationary in 64 VGPRs (loads hit L2; A = 256 KB)
        float Areg[64];
#pragma unroll
        for (int jj = 0; jj < 64; ++jj)
            Areg[jj] = A[(size_t)(j0 + jj) * K + k];

        // reduce the 256 partial slots (64 per jc group)
        {
            float m = 0.f;
            for (int c = j0; c < j0 + 64; ++c)
                m = fmaxf(m, partials[((size_t)c * BATCH + b) * K + k]);
            red[jc][k] = m;
        }
        if (tid < HID)
            ce_red[tid] = cell_emb[cell_idx[b] * HID + tid] * W2[tid];
        __syncthreads();
        if (jc == 0) {
            float s = fmaxf(fmaxf(red[0][k], red[1][k]),
                            fmaxf(red[2][k], red[3][k]));
            Sm[k] = s;
            ((float*)zb)[k] = s;          // zb[0] = Z0 = S
        }
        if (tid == 0) {
            float s = b2[0];
            for (int h = 0; h < HID; ++h) s += ce_red[h];
            ce_dot[b] = s;
        }
        __syncthreads();

        for (int s = 0; s < STEPS; ++s) {
            const float4* cur4 = zb[s & 1] + (j0 >> 2);
            float*        nxt  = (float*)zb[(s + 1) & 1];
            float acc = 0.f;
#pragma unroll
            for (int q = 0; q < 16; ++q) {
                float4 c4 = cur4[q];               // LDS broadcast, b128
                acc = fmaf(c4.x, Areg[4*q + 0], acc);
                acc = fmaf(c4.y, Areg[4*q + 1], acc);
                acc = fmaf(c4.z, Areg[4*q + 2], acc);
                acc = fmaf(c4.w, Areg[4*q + 3], acc);
            }
            red[jc][k] = acc;
            __syncthreads();
            if (jc == 0)
                nxt[k] = 0.9f * (red[0][k] + red[1][k] + red[2][k] + red[3][k])
                       + 0.1f * Sm[k];
            __syncthreads();
        }
        if (jc == 0) Zfin[b * K + k] = ((float*)zb)[k];   // 10 even steps -> zb[0]
    }
    grid.sync();

    // ================= Phase 3: final (blocks 0..78) =================
    if (blk < (G + 63) / 64) {
        const float4* Z4 = (const float4*)Zfin;
        for (int i = tid; i < BATCH * (K/4); i += NTHR) zl[i] = Z4[i];
        if (tid < HID) {
            wpack[tid] = make_float4(W1[tid], W1[HID + tid], W1[2*HID + tid], b1[tid]);
            w2l[tid] = W2[tid];
        }
        __syncthreads();

        const int gl = tid & 63;
        const int b  = tid >> 6;          // 0..15, wave-uniform
        const int g  = blk * 64 + gl;
        if (g < G) {
            float acc = 0.f;
            const float4* M4   = (const float4*)(M + (size_t)g * K);
            const float4* zrow = &zl[b * (K/4)];
#pragma unroll 8
            for (int k4 = 0; k4 < K/4; ++k4) {
                float4 m4 = M4[k4];
                float4 z4 = zrow[k4];     // LDS broadcast (b uniform per wave)
                acc = fmaf(m4.x, z4.x, acc);
                acc = fmaf(m4.y, z4.y, acc);
                acc = fmaf(m4.z, z4.z, acc);
                acc = fmaf(m4.w, z4.w, acc);
            }
            float cv = ctl[b * G + g];    // coalesced across gl
            float tv = tgt[b * G + g];
            float y  = ce_dot[b];         // wave-uniform broadcast
#pragma unroll 4
            for (int h = 0; h < HID; ++h) {
                float4 w = wpack[h];
                float pre = fmaf(cv, w.x, w.w);
                pre = fmaf(tv, w.y, pre);
                pre = fmaf(acc, w.z, pre);
                pre = fmaxf(pre, 0.f);
                y = fmaf(pre, w2l[h], y);
            }
            out[b * G + g] = y;
        }
    }
}

// ---------------------------------------------------------------------------
extern "C" void kernel_launch(void* const* d_in, const int* in_sizes, int n_in,
                              void* d_out, int out_size, void* d_ws, size_t ws_size,
                              hipStream_t stream) {
    const float* ctl      = (const float*)d_in[0];
    const float* tgt      = (const float*)d_in[1];
    const int*   cell_idx = (const int*)d_in[2];
    // d_in[3] = drug_fp (unused by the reference output)
    const float* M        = (const float*)d_in[4];
    const float* A        = (const float*)d_in[5];
    const float* W1       = (const float*)d_in[6];
    const float* b1       = (const float*)d_in[7];
    const float* cell_emb = (const float*)d_in[8];
    const float* W2       = (const float*)d_in[9];
    const float* b2       = (const float*)d_in[10];
    float* out = (float*)d_out;

    float* partials = (float*)d_ws;                      // 4 MB
    float* Zfin     = partials + (size_t)NCP * BATCH * K;
    float* ce       = Zfin + BATCH * K;

    void* args[] = {
        (void*)&ctl, (void*)&tgt, (void*)&cell_idx, (void*)&M, (void*)&A,
        (void*)&W1, (void*)&b1, (void*)&cell_emb, (void*)&W2, (void*)&b2,
        (void*)&out, (void*)&partials, (void*)&Zfin, (void*)&ce
    };
    hipLaunchCooperativeKernel((const void*)fused_all, dim3(NBLK), dim3(NTHR),
                               args, 0, stream);
}